// Round 1
// baseline (168.316 us; speedup 1.0000x reference)
//
#include <hip/hip_runtime.h>

// ---------------- workspace layout (float offsets) ----------------
// V  : 2^14 x 16 vectors  (bits t=0..13, includes left fold)
// W  : 2^14 x 16 vectors  (bits t=50..63, includes right fold)
// P  : 4 chunks x 2^9 x 16x16 matrices (bits t=14+9c .. 22+9c)
// build pieces: VA/WB 7-bit vector chains, PAV/PAW 7-bit matrix products,
// PC0 5-bit / PC1 4-bit matrix products per chunk.
#define OFF_V    0u
#define OFF_W    262144u
#define OFF_P    524288u
#define OFF_VA   1048576u
#define OFF_WB   1050624u
#define OFF_PAV  1052672u
#define OFF_PAW  1085440u
#define OFF_PC0  1118208u
#define OFF_PC1  1150976u
// total 1167360 floats = 4.46 MB of d_ws

__device__ __forceinline__ void rmul16(float* v, const float* B) {
  // v <- v * B   (row-vector times matrix, B[d*16+e])
  float nv[16];
#pragma unroll
  for (int e = 0; e < 16; ++e) {
    float a = 0.f;
#pragma unroll
    for (int d = 0; d < 16; ++d) a = fmaf(v[d], B[d * 16 + e], a);
    nv[e] = a;
  }
#pragma unroll
  for (int e = 0; e < 16; ++e) v[e] = nv[e];
}

__device__ __forceinline__ void lmul16(float* v, const float* B) {
  // v <- B * v   (matrix times column-vector)
  float nv[16];
#pragma unroll
  for (int d = 0; d < 16; ++d) {
    float a = 0.f;
#pragma unroll
    for (int e = 0; e < 16; ++e) a = fmaf(B[d * 16 + e], v[e], a);
    nv[d] = a;
  }
#pragma unroll
  for (int d = 0; d < 16; ++d) v[d] = nv[d];
}

// ---------------- phase A: small-depth piece chains ----------------
// grid: 29 blocks x 256 = 7424 threads, one piece each
__global__ __launch_bounds__(256) void build_a(const float* __restrict__ left,
                                               const float* __restrict__ bulk,
                                               const float* __restrict__ right,
                                               float* __restrict__ ws) {
  __shared__ float Bs[2][256];  // Bs[s][d*16+e] = bulk[d][e][s]
  __shared__ float Ls[2][16];   // Ls[s][d] = left[0][d][s]
  __shared__ float Rs[2][16];   // Rs[s][d] = right[d][0][s]
  int tid = threadIdx.x;
  for (int i = tid; i < 576; i += 256) {
    if (i < 512) Bs[i & 1][i >> 1] = bulk[i];
    else if (i < 544) { int j = i - 512; Ls[j & 1][j >> 1] = left[j]; }
    else              { int j = i - 544; Rs[j & 1][j >> 1] = right[j]; }
  }
  __syncthreads();

  unsigned gid = blockIdx.x * 256 + tid;
  float v[16];
  if (gid < 128) {
    // VA[i]: bits 0..6 <-> t=0..6 (left fold at t=0)
    unsigned i = gid;
#pragma unroll
    for (int d = 0; d < 16; ++d) v[d] = Ls[i & 1][d];
    for (int t = 1; t <= 6; ++t) rmul16(v, Bs[(i >> t) & 1]);
#pragma unroll
    for (int d = 0; d < 16; ++d) ws[OFF_VA + i * 16 + d] = v[d];
  } else if (gid < 256) {
    // WB[i]: bits 0..6 <-> t=57..63 (right fold at t=63, bit 6)
    unsigned i = gid - 128;
#pragma unroll
    for (int d = 0; d < 16; ++d) v[d] = Rs[(i >> 6) & 1][d];
    for (int p = 5; p >= 0; --p) lmul16(v, Bs[(i >> p) & 1]);
#pragma unroll
    for (int d = 0; d < 16; ++d) ws[OFF_WB + i * 16 + d] = v[d];
  } else if (gid < 2304) {
    // PAV[i] column chains: bits 0..6 <-> t=7..13; column col of product
    unsigned it = gid - 256, i = it >> 4, col = it & 15;
#pragma unroll
    for (int d = 0; d < 16; ++d) v[d] = Bs[(i >> 6) & 1][d * 16 + col];
    for (int p = 5; p >= 0; --p) lmul16(v, Bs[(i >> p) & 1]);
#pragma unroll
    for (int d = 0; d < 16; ++d) ws[OFF_PAV + i * 256 + d * 16 + col] = v[d];
  } else if (gid < 4352) {
    // PAW[i] column chains: bits 0..6 <-> t=50..56
    unsigned it = gid - 2304, i = it >> 4, col = it & 15;
#pragma unroll
    for (int d = 0; d < 16; ++d) v[d] = Bs[(i >> 6) & 1][d * 16 + col];
    for (int p = 5; p >= 0; --p) lmul16(v, Bs[(i >> p) & 1]);
#pragma unroll
    for (int d = 0; d < 16; ++d) ws[OFF_PAW + i * 256 + d * 16 + col] = v[d];
  } else {
    // chunk pieces: per chunk c (t0 = 14+9c): PC0 over bits 0..4, PC1 over bits 5..8
    unsigned it = gid - 4352, c = it / 768, r = it - c * 768;
    if (r < 512) {
      unsigned i = r >> 4, col = r & 15;  // 5-bit piece, t0..t0+4
#pragma unroll
      for (int d = 0; d < 16; ++d) v[d] = Bs[(i >> 4) & 1][d * 16 + col];
      for (int p = 3; p >= 0; --p) lmul16(v, Bs[(i >> p) & 1]);
#pragma unroll
      for (int d = 0; d < 16; ++d) ws[OFF_PC0 + c * 8192 + i * 256 + d * 16 + col] = v[d];
    } else {
      unsigned r2 = r - 512, i = r2 >> 4, col = r2 & 15;  // 4-bit piece, t0+5..t0+8
#pragma unroll
      for (int d = 0; d < 16; ++d) v[d] = Bs[(i >> 3) & 1][d * 16 + col];
      for (int p = 2; p >= 0; --p) lmul16(v, Bs[(i >> p) & 1]);
#pragma unroll
      for (int d = 0; d < 16; ++d) ws[OFF_PC1 + c * 4096 + i * 256 + d * 16 + col] = v[d];
    }
  }
}

// ---------------- phase B: massively parallel combines ----------------
// grid: 4096 x 256 = 1048576 threads
__global__ __launch_bounds__(256) void build_b(float* __restrict__ ws) {
  unsigned gid = blockIdx.x * 256 + threadIdx.x;
  if (gid < 262144u) {
    // V[i][e] = sum_k VA[i&127][k] * PAV[i>>7][k][e]
    unsigned i = gid >> 4, e = gid & 15;
    const float* va = ws + OFF_VA + (i & 127) * 16;
    const float* pm = ws + OFF_PAV + (i >> 7) * 256;
    float a = 0.f;
#pragma unroll
    for (int k = 0; k < 16; ++k) a = fmaf(va[k], pm[k * 16 + e], a);
    ws[OFF_V + (size_t)i * 16 + e] = a;
  } else if (gid < 524288u) {
    // W[i][d] = sum_k PAW[i&127][d][k] * WB[i>>7][k]
    unsigned g = gid - 262144u, i = g >> 4, d = g & 15;
    const float* wb = ws + OFF_WB + (i >> 7) * 16;
    const float* pm = ws + OFF_PAW + (i & 127) * 256 + d * 16;
    float a = 0.f;
#pragma unroll
    for (int k = 0; k < 16; ++k) a = fmaf(pm[k], wb[k], a);
    ws[OFF_W + (size_t)i * 16 + d] = a;
  } else {
    // P_c[idx][d][e] = sum_k PC0[c][idx&31][d][k] * PC1[c][idx>>5][k][e]
    unsigned g = gid - 524288u;
    unsigned c = g >> 17, rem = g & 131071u;
    unsigned idx = rem >> 8, d = (rem >> 4) & 15, e = rem & 15;
    const float* p0 = ws + OFF_PC0 + c * 8192 + (idx & 31) * 256 + d * 16;
    const float* p1 = ws + OFF_PC1 + c * 4096 + (idx >> 5) * 256 + e;
    float a = 0.f;
#pragma unroll
    for (int k = 0; k < 16; ++k) a = fmaf(p0[k], p1[k * 16], a);
    ws[OFF_P + ((size_t)c << 17) + (size_t)idx * 256 + d * 16 + e] = a;
  }
}

// ---------------- main kernel ----------------
// block 256 = 4 waves; each wave handles 64 sequences (one per lane)
__global__ __launch_bounds__(256) void mps_main(const int* __restrict__ x,
                                                const float* __restrict__ ws,
                                                float* __restrict__ out) {
  int lane = threadIdx.x & 63;
  int wave = threadIdx.x >> 6;
  unsigned seqbase = blockIdx.x * 256u + wave * 64u;

  // ballot-transpose bit packing: lane = column t, iterate rows (sequences).
  // mask bit l = x[row][l] -> packed 64-bit word for that row's sequence.
  const int* __restrict__ xp = x + (size_t)seqbase * 64;
  unsigned long long bits = 0ull;
#pragma unroll
  for (int rb = 0; rb < 8; ++rb) {
    int vals[8];
#pragma unroll
    for (int j = 0; j < 8; ++j) vals[j] = xp[(size_t)(rb * 8 + j) * 64 + lane];
#pragma unroll
    for (int j = 0; j < 8; ++j) {
      unsigned long long mm = __ballot(vals[j] & 1);
      if (lane == rb * 8 + j) bits = mm;
    }
  }

  // V lookup (bits 0..13)
  float m[16];
  {
    unsigned i0 = (unsigned)(bits & 0x3FFFull);
    const float4* vp = reinterpret_cast<const float4*>(ws + OFF_V) + (size_t)i0 * 4;
    float4 a = vp[0], b = vp[1], c = vp[2], d = vp[3];
    m[0] = a.x; m[1] = a.y; m[2] = a.z; m[3] = a.w;
    m[4] = b.x; m[5] = b.y; m[6] = b.z; m[7] = b.w;
    m[8] = c.x; m[9] = c.y; m[10] = c.z; m[11] = c.w;
    m[12] = d.x; m[13] = d.y; m[14] = d.z; m[15] = d.w;
  }

  // 4 chunk matvecs (9 bits each, t=14..49)
#pragma unroll
  for (int ch = 0; ch < 4; ++ch) {
    unsigned idx = (unsigned)((bits >> (14 + 9 * ch)) & 511ull);
    const float4* pp = reinterpret_cast<const float4*>(ws + OFF_P + ((size_t)ch << 17)) +
                       (size_t)idx * 64;
    float acc[16];
#pragma unroll
    for (int e = 0; e < 16; ++e) acc[e] = 0.f;
#pragma unroll
    for (int d = 0; d < 16; ++d) {
      float4 r0 = pp[d * 4 + 0], r1 = pp[d * 4 + 1], r2 = pp[d * 4 + 2], r3 = pp[d * 4 + 3];
      float s = m[d];
      acc[0]  = fmaf(s, r0.x, acc[0]);  acc[1]  = fmaf(s, r0.y, acc[1]);
      acc[2]  = fmaf(s, r0.z, acc[2]);  acc[3]  = fmaf(s, r0.w, acc[3]);
      acc[4]  = fmaf(s, r1.x, acc[4]);  acc[5]  = fmaf(s, r1.y, acc[5]);
      acc[6]  = fmaf(s, r1.z, acc[6]);  acc[7]  = fmaf(s, r1.w, acc[7]);
      acc[8]  = fmaf(s, r2.x, acc[8]);  acc[9]  = fmaf(s, r2.y, acc[9]);
      acc[10] = fmaf(s, r2.z, acc[10]); acc[11] = fmaf(s, r2.w, acc[11]);
      acc[12] = fmaf(s, r3.x, acc[12]); acc[13] = fmaf(s, r3.y, acc[13]);
      acc[14] = fmaf(s, r3.z, acc[14]); acc[15] = fmaf(s, r3.w, acc[15]);
    }
#pragma unroll
    for (int e = 0; e < 16; ++e) m[e] = acc[e];
  }

  // W dot (bits 50..63)
  float a;
  {
    unsigned iw = (unsigned)(bits >> 50);
    const float4* wp = reinterpret_cast<const float4*>(ws + OFF_W) + (size_t)iw * 4;
    float4 w0 = wp[0], w1 = wp[1], w2 = wp[2], w3 = wp[3];
    a = m[0] * w0.x + m[1] * w0.y + m[2] * w0.z + m[3] * w0.w;
    a = fmaf(m[4], w1.x, a);  a = fmaf(m[5], w1.y, a);
    a = fmaf(m[6], w1.z, a);  a = fmaf(m[7], w1.w, a);
    a = fmaf(m[8], w2.x, a);  a = fmaf(m[9], w2.y, a);
    a = fmaf(m[10], w2.z, a); a = fmaf(m[11], w2.w, a);
    a = fmaf(m[12], w3.x, a); a = fmaf(m[13], w3.y, a);
    a = fmaf(m[14], w3.z, a); a = fmaf(m[15], w3.w, a);
  }
  out[seqbase + lane] = a;
}

extern "C" void kernel_launch(void* const* d_in, const int* in_sizes, int n_in,
                              void* d_out, int out_size, void* d_ws, size_t ws_size,
                              hipStream_t stream) {
  const int* x = (const int*)d_in[0];
  const float* left = (const float*)d_in[1];
  const float* bulk = (const float*)d_in[2];
  const float* right = (const float*)d_in[3];
  float* out = (float*)d_out;
  float* ws = (float*)d_ws;

  int nseq = in_sizes[0] / 64;  // 131072

  build_a<<<29, 256, 0, stream>>>(left, bulk, right, ws);
  build_b<<<4096, 256, 0, stream>>>(ws);
  mps_main<<<nseq / 256, 256, 0, stream>>>(x, ws, out);
}

// Round 2
// 119.503 us; speedup vs baseline: 1.4085x; 1.4085x over previous
//
#include <hip/hip_runtime.h>

// ---------------- workspace layout (float offsets) ----------------
// V  : 2^14 x 16 vectors  (bits t=0..13, includes left fold)
// W  : 2^14 x 16 vectors  (bits t=50..63, includes right fold)
// P  : 4 chunks x 2^9 x 16x16 matrices (bits t=14+9c .. 22+9c)
#define OFF_V    0u
#define OFF_W    262144u
#define OFF_P    524288u
#define OFF_VA   1048576u
#define OFF_WB   1050624u
#define OFF_PAV  1052672u
#define OFF_PAW  1085440u
#define OFF_PC0  1118208u
#define OFF_PC1  1150976u
// total 1167360 floats = 4.46 MB of d_ws

__device__ __forceinline__ void rmul16(float* v, const float* B) {
  float nv[16];
#pragma unroll
  for (int e = 0; e < 16; ++e) {
    float a = 0.f;
#pragma unroll
    for (int d = 0; d < 16; ++d) a = fmaf(v[d], B[d * 16 + e], a);
    nv[e] = a;
  }
#pragma unroll
  for (int e = 0; e < 16; ++e) v[e] = nv[e];
}

__device__ __forceinline__ void lmul16(float* v, const float* B) {
  float nv[16];
#pragma unroll
  for (int d = 0; d < 16; ++d) {
    float a = 0.f;
#pragma unroll
    for (int e = 0; e < 16; ++e) a = fmaf(B[d * 16 + e], v[e], a);
    nv[d] = a;
  }
#pragma unroll
  for (int d = 0; d < 16; ++d) v[d] = nv[d];
}

// ---------------- phase A: small-depth piece chains ----------------
__global__ __launch_bounds__(256) void build_a(const float* __restrict__ left,
                                               const float* __restrict__ bulk,
                                               const float* __restrict__ right,
                                               float* __restrict__ ws) {
  __shared__ float Bs[2][256];
  __shared__ float Ls[2][16];
  __shared__ float Rs[2][16];
  int tid = threadIdx.x;
  for (int i = tid; i < 576; i += 256) {
    if (i < 512) Bs[i & 1][i >> 1] = bulk[i];
    else if (i < 544) { int j = i - 512; Ls[j & 1][j >> 1] = left[j]; }
    else              { int j = i - 544; Rs[j & 1][j >> 1] = right[j]; }
  }
  __syncthreads();

  unsigned gid = blockIdx.x * 256 + tid;
  float v[16];
  if (gid < 128) {
    unsigned i = gid;
#pragma unroll
    for (int d = 0; d < 16; ++d) v[d] = Ls[i & 1][d];
    for (int t = 1; t <= 6; ++t) rmul16(v, Bs[(i >> t) & 1]);
#pragma unroll
    for (int d = 0; d < 16; ++d) ws[OFF_VA + i * 16 + d] = v[d];
  } else if (gid < 256) {
    unsigned i = gid - 128;
#pragma unroll
    for (int d = 0; d < 16; ++d) v[d] = Rs[(i >> 6) & 1][d];
    for (int p = 5; p >= 0; --p) lmul16(v, Bs[(i >> p) & 1]);
#pragma unroll
    for (int d = 0; d < 16; ++d) ws[OFF_WB + i * 16 + d] = v[d];
  } else if (gid < 2304) {
    unsigned it = gid - 256, i = it >> 4, col = it & 15;
#pragma unroll
    for (int d = 0; d < 16; ++d) v[d] = Bs[(i >> 6) & 1][d * 16 + col];
    for (int p = 5; p >= 0; --p) lmul16(v, Bs[(i >> p) & 1]);
#pragma unroll
    for (int d = 0; d < 16; ++d) ws[OFF_PAV + i * 256 + d * 16 + col] = v[d];
  } else if (gid < 4352) {
    unsigned it = gid - 2304, i = it >> 4, col = it & 15;
#pragma unroll
    for (int d = 0; d < 16; ++d) v[d] = Bs[(i >> 6) & 1][d * 16 + col];
    for (int p = 5; p >= 0; --p) lmul16(v, Bs[(i >> p) & 1]);
#pragma unroll
    for (int d = 0; d < 16; ++d) ws[OFF_PAW + i * 256 + d * 16 + col] = v[d];
  } else {
    unsigned it = gid - 4352, c = it / 768, r = it - c * 768;
    if (r < 512) {
      unsigned i = r >> 4, col = r & 15;
#pragma unroll
      for (int d = 0; d < 16; ++d) v[d] = Bs[(i >> 4) & 1][d * 16 + col];
      for (int p = 3; p >= 0; --p) lmul16(v, Bs[(i >> p) & 1]);
#pragma unroll
      for (int d = 0; d < 16; ++d) ws[OFF_PC0 + c * 8192 + i * 256 + d * 16 + col] = v[d];
    } else {
      unsigned r2 = r - 512, i = r2 >> 4, col = r2 & 15;
#pragma unroll
      for (int d = 0; d < 16; ++d) v[d] = Bs[(i >> 3) & 1][d * 16 + col];
      for (int p = 2; p >= 0; --p) lmul16(v, Bs[(i >> p) & 1]);
#pragma unroll
      for (int d = 0; d < 16; ++d) ws[OFF_PC1 + c * 4096 + i * 256 + d * 16 + col] = v[d];
    }
  }
}

// ---------------- phase B: massively parallel combines ----------------
__global__ __launch_bounds__(256) void build_b(float* __restrict__ ws) {
  unsigned gid = blockIdx.x * 256 + threadIdx.x;
  if (gid < 262144u) {
    unsigned i = gid >> 4, e = gid & 15;
    const float* va = ws + OFF_VA + (i & 127) * 16;
    const float* pm = ws + OFF_PAV + (i >> 7) * 256;
    float a = 0.f;
#pragma unroll
    for (int k = 0; k < 16; ++k) a = fmaf(va[k], pm[k * 16 + e], a);
    ws[OFF_V + (size_t)i * 16 + e] = a;
  } else if (gid < 524288u) {
    unsigned g = gid - 262144u, i = g >> 4, d = g & 15;
    const float* wb = ws + OFF_WB + (i >> 7) * 16;
    const float* pm = ws + OFF_PAW + (i & 127) * 256 + d * 16;
    float a = 0.f;
#pragma unroll
    for (int k = 0; k < 16; ++k) a = fmaf(pm[k], wb[k], a);
    ws[OFF_W + (size_t)i * 16 + d] = a;
  } else {
    unsigned g = gid - 524288u;
    unsigned c = g >> 17, rem = g & 131071u;
    unsigned idx = rem >> 8, d = (rem >> 4) & 15, e = rem & 15;
    const float* p0 = ws + OFF_PC0 + c * 8192 + (idx & 31) * 256 + d * 16;
    const float* p1 = ws + OFF_PC1 + c * 4096 + (idx >> 5) * 256 + e;
    float a = 0.f;
#pragma unroll
    for (int k = 0; k < 16; ++k) a = fmaf(p0[k], p1[k * 16], a);
    ws[OFF_P + ((size_t)c << 17) + (size_t)idx * 256 + d * 16 + e] = a;
  }
}

// ---------------- main kernel: 16 lanes per sequence ----------------
// block 256 = 4 waves; each wave handles 4 sequences (lane e = output elem).
// All 4 chunk operand columns (64 scalars/lane) loaded upfront for MLP;
// per-chunk m-broadcast via wave-synchronous LDS roundtrip (no barrier).
__global__ __launch_bounds__(256, 4) void mps_main(const int* __restrict__ x,
                                                   const float* __restrict__ ws,
                                                   float* __restrict__ out) {
  __shared__ float sm[4][4][16];
  const int tid = threadIdx.x;
  const int lane = tid & 63;
  const int wave = tid >> 6;
  const int grp = lane >> 4;
  const int e = lane & 15;
  const unsigned seqw = blockIdx.x * 16u + wave * 4u;  // first seq of this wave
  const int* __restrict__ xp = x + (size_t)seqw * 64;

  // coalesced ballot-transpose: lane = column t, one row per ballot
  int v0 = xp[lane];
  int v1 = xp[64 + lane];
  int v2 = xp[128 + lane];
  int v3 = xp[192 + lane];
  unsigned long long b0 = __ballot(v0 & 1);
  unsigned long long b1 = __ballot(v1 & 1);
  unsigned long long b2 = __ballot(v2 & 1);
  unsigned long long b3 = __ballot(v3 & 1);
  unsigned long long bits = (grp & 2) ? ((grp & 1) ? b3 : b2)
                                      : ((grp & 1) ? b1 : b0);

  const unsigned i0 = (unsigned)(bits & 0x3FFFull);
  const unsigned iw = (unsigned)(bits >> 50);
  unsigned idx0 = (unsigned)((bits >> 14) & 511ull);
  unsigned idx1 = (unsigned)((bits >> 23) & 511ull);
  unsigned idx2 = (unsigned)((bits >> 32) & 511ull);
  unsigned idx3 = (unsigned)((bits >> 41) & 511ull);

  // issue ALL gathers upfront (V, W, 4x16 chunk columns) — max MLP,
  // each instruction is a 64B-coalesced line per 16-lane group
  float mv = ws[OFF_V + (size_t)i0 * 16 + e];
  float w  = ws[OFF_W + (size_t)iw * 16 + e];

  const float* __restrict__ P0 = ws + OFF_P;
  float p[4][16];
  {
    const float* pb = P0 + (size_t)idx0 * 256 + e;
#pragma unroll
    for (int d = 0; d < 16; ++d) p[0][d] = pb[d * 16];
  }
  {
    const float* pb = P0 + (1u << 17) + (size_t)idx1 * 256 + e;
#pragma unroll
    for (int d = 0; d < 16; ++d) p[1][d] = pb[d * 16];
  }
  {
    const float* pb = P0 + (2u << 17) + (size_t)idx2 * 256 + e;
#pragma unroll
    for (int d = 0; d < 16; ++d) p[2][d] = pb[d * 16];
  }
  {
    const float* pb = P0 + (3u << 17) + (size_t)idx3 * 256 + e;
#pragma unroll
    for (int d = 0; d < 16; ++d) p[3][d] = pb[d * 16];
  }

#pragma unroll
  for (int ch = 0; ch < 4; ++ch) {
    // wave-synchronous broadcast of m within each 16-lane group:
    // DS ops from one wave complete in order; asm barriers stop reordering.
    sm[wave][grp][e] = mv;
    asm volatile("" ::: "memory");
    float4 M0 = *(const float4*)&sm[wave][grp][0];
    float4 M1 = *(const float4*)&sm[wave][grp][4];
    float4 M2 = *(const float4*)&sm[wave][grp][8];
    float4 M3 = *(const float4*)&sm[wave][grp][12];
    asm volatile("" ::: "memory");
    float a0 = M0.x * p[ch][0];
    float a1 = M0.y * p[ch][1];
    float a2 = M0.z * p[ch][2];
    float a3 = M0.w * p[ch][3];
    a0 = fmaf(M1.x, p[ch][4], a0);
    a1 = fmaf(M1.y, p[ch][5], a1);
    a2 = fmaf(M1.z, p[ch][6], a2);
    a3 = fmaf(M1.w, p[ch][7], a3);
    a0 = fmaf(M2.x, p[ch][8], a0);
    a1 = fmaf(M2.y, p[ch][9], a1);
    a2 = fmaf(M2.z, p[ch][10], a2);
    a3 = fmaf(M2.w, p[ch][11], a3);
    a0 = fmaf(M3.x, p[ch][12], a0);
    a1 = fmaf(M3.y, p[ch][13], a1);
    a2 = fmaf(M3.z, p[ch][14], a2);
    a3 = fmaf(M3.w, p[ch][15], a3);
    mv = (a0 + a1) + (a2 + a3);
  }

  // final dot with W vector, reduce across the 16-lane group
  float part = mv * w;
  part += __shfl_xor(part, 1, 64);
  part += __shfl_xor(part, 2, 64);
  part += __shfl_xor(part, 4, 64);
  part += __shfl_xor(part, 8, 64);
  if (e == 0) out[seqw + grp] = part;
}

extern "C" void kernel_launch(void* const* d_in, const int* in_sizes, int n_in,
                              void* d_out, int out_size, void* d_ws, size_t ws_size,
                              hipStream_t stream) {
  const int* x = (const int*)d_in[0];
  const float* left = (const float*)d_in[1];
  const float* bulk = (const float*)d_in[2];
  const float* right = (const float*)d_in[3];
  float* out = (float*)d_out;
  float* ws = (float*)d_ws;

  int nseq = in_sizes[0] / 64;  // 131072

  build_a<<<29, 256, 0, stream>>>(left, bulk, right, ws);
  build_b<<<4096, 256, 0, stream>>>(ws);
  mps_main<<<nseq / 16, 256, 0, stream>>>(x, ws, out);
}